// Round 5
// baseline (250.906 us; speedup 1.0000x reference)
//
#include <hip/hip_runtime.h>
#include <hip/hip_bf16.h>
#include <math.h>

// ---------------------------------------------------------------------------
// AdvancedGCN on MI355X — round 5:
//  * own zero kernel instead of hipMemsetAsync (rocclr fill cost 42us!)
//  * GEMM: padded transposed Xs (kills 8-way staging conflicts),
//          split-half column assignment (W-read 4-way -> 2-way),
//          register double-buffered staging (hide HBM latency under FMAs)
// ---------------------------------------------------------------------------

#define BN_EPS 1e-5f

static __device__ __forceinline__ float bf2f(unsigned int u16) {
    return __uint_as_float(u16 << 16);
}
static __device__ __forceinline__ unsigned short f2bf(float f) {
    unsigned int b = __float_as_uint(f);
    return (unsigned short)((b + 0x7FFFu + ((b >> 16) & 1u)) >> 16);
}
static __device__ __forceinline__ void unpack8(uint4 u, float* f) {
    f[0] = bf2f(u.x & 0xffffu); f[1] = bf2f(u.x >> 16);
    f[2] = bf2f(u.y & 0xffffu); f[3] = bf2f(u.y >> 16);
    f[4] = bf2f(u.z & 0xffffu); f[5] = bf2f(u.z >> 16);
    f[6] = bf2f(u.w & 0xffffu); f[7] = bf2f(u.w >> 16);
}

// --------------------------- CSR build kernels -----------------------------
__global__ void zero_counts_kernel(int* __restrict__ counts, int N) {
    int i = blockIdx.x * 256 + threadIdx.x;
    if (i < N) counts[i] = 0;
}

// rank[e] = position of edge e within its dst bucket; counts -> in-degrees.
__global__ void rank_hist_kernel(const int* __restrict__ dst, int* __restrict__ counts,
                                 int* __restrict__ rank, int E) {
    int e = blockIdx.x * 256 + threadIdx.x;
    if (e < E) rank[e] = atomicAdd(&counts[dst[e]], 1);
}

// block-level inclusive scan -> per-element exclusive + block sums
__global__ void scan_block_kernel(const int* __restrict__ counts, int* __restrict__ excl,
                                  int* __restrict__ bsum, int N) {
    __shared__ int s[256];
    int tid = threadIdx.x;
    int i = blockIdx.x * 256 + tid;
    int v = (i < N) ? counts[i] : 0;
    s[tid] = v;
    __syncthreads();
#pragma unroll
    for (int off = 1; off < 256; off <<= 1) {
        int t = (tid >= off) ? s[tid - off] : 0;
        __syncthreads();
        s[tid] += t;
        __syncthreads();
    }
    if (i < N) excl[i] = s[tid] - v;
    if (tid == 255) bsum[blockIdx.x] = s[255];
}

// finalize: each block re-scans the (<=256) block sums in LDS, then
// rowptr[i] = excl[i] + excl_block_sum; dinv = rsqrt(indeg + 1).
__global__ void scan_add_kernel(const int* __restrict__ excl, const int* __restrict__ bsum,
                                const int* __restrict__ counts,
                                int* __restrict__ rowptr, float* __restrict__ dinv,
                                int nb, int N, int E) {
    __shared__ int sb[256];
    int tid = threadIdx.x;
    int v = (tid < nb) ? bsum[tid] : 0;
    sb[tid] = v;
    __syncthreads();
#pragma unroll
    for (int off = 1; off < 256; off <<= 1) {
        int t = (tid >= off) ? sb[tid - off] : 0;
        __syncthreads();
        sb[tid] += t;
        __syncthreads();
    }
    int eb = sb[blockIdx.x] - ((blockIdx.x < nb) ? bsum[blockIdx.x] : 0);  // exclusive
    int i = blockIdx.x * 256 + tid;
    if (i < N) {
        rowptr[i] = excl[i] + eb;
        dinv[i]   = rsqrtf((float)counts[i] + 1.0f);
    }
    if (i == N) rowptr[N] = E;
}

// atomic-free fill: csr[rowptr[d] + rank[e]] = src[e]
__global__ void fill_csr_kernel(const int* __restrict__ src, const int* __restrict__ dst,
                                const int* __restrict__ rank, const int* __restrict__ rowptr,
                                int* __restrict__ csr, int E) {
    int e = blockIdx.x * 256 + threadIdx.x;
    if (e >= E) return;
    csr[rowptr[dst[e]] + rank[e]] = src[e];
}

// ----------------------------- dual GEMM -----------------------------------
// H(bf16)[N,M1] = X @ Wc   (conv path, pre-bias, pre-norm)
// SK(f32)[N,M2] = X @ Wsk + skb  (skip path; M2 == 0 -> disabled)
// Each thread: RT=4 rows x 8 cols, cols split into two half-tiles
// (c0 = j*4, c1 = M/2 + j*4) so W LDS reads are 2-way-conflict-free.
// Register double-buffer: tile k+1 loaded to VGPRs while computing tile k.
template <int K, int M1, int M2>
__launch_bounds__(256)
__global__ void gemm_kernel(const float* __restrict__ X,
                            const float* __restrict__ Wc,
                            const float* __restrict__ Wsk, const float* __restrict__ skb,
                            unsigned short* __restrict__ H, float* __restrict__ SK, int N)
{
    constexpr int M    = M1 + M2;
    constexpr int COLT = M / 8;              // 16 (M=128) / 8 (M=64)
    constexpr int RT   = 4;
    constexpr int TR   = (256 / COLT) * RT;  // 64 / 128
    constexpr int KC   = 32;
    constexpr int NXV  = TR * KC / 1024;     // float4s per thread (X tile)
    constexpr int NWV  = KC * M / 1024;      // float4s per thread (W tile)
    constexpr int HALF = M / 2;

    __shared__ float Xs[KC][TR + 1];         // transposed, +1 pad kills conflicts
    __shared__ float Ws[KC][M + 4];

    const int tid = threadIdx.x;
    const int i   = tid / COLT;
    const int j   = tid % COLT;
    const int r0  = blockIdx.x * TR;
    const int c0  = j * 4;
    const int c1  = HALF + j * 4;

    float4 xv[NXV], wv[NWV];

    auto loadX = [&](int k0) {
#pragma unroll
        for (int l = 0; l < NXV; ++l) {
            int f   = tid + 256 * l;
            int row = f >> 3;
            int kq  = f & 7;
            xv[l] = (r0 + row < N) ? *(const float4*)&X[(size_t)(r0 + row) * K + k0 + kq * 4]
                                   : make_float4(0.f, 0.f, 0.f, 0.f);
        }
    };
    auto loadW = [&](int k0) {
#pragma unroll
        for (int l = 0; l < NWV; ++l) {
            int f   = tid + 256 * l;
            int kr  = f / (M / 4);
            int col = (f % (M / 4)) * 4;
            if (M2 == 0 || col < M1)
                wv[l] = *(const float4*)&Wc[(size_t)(k0 + kr) * M1 + col];
            else
                wv[l] = *(const float4*)&Wsk[(size_t)(k0 + kr) * M2 + (col - M1)];
        }
    };
    auto stash = [&]() {
#pragma unroll
        for (int l = 0; l < NXV; ++l) {
            int f   = tid + 256 * l;
            int row = f >> 3;
            int kq  = f & 7;
            Xs[kq * 4 + 0][row] = xv[l].x;
            Xs[kq * 4 + 1][row] = xv[l].y;
            Xs[kq * 4 + 2][row] = xv[l].z;
            Xs[kq * 4 + 3][row] = xv[l].w;
        }
#pragma unroll
        for (int l = 0; l < NWV; ++l) {
            int f   = tid + 256 * l;
            int kr  = f / (M / 4);
            int col = (f % (M / 4)) * 4;
            *(float4*)&Ws[kr][col] = wv[l];
        }
    };

    float acc[RT][8];
#pragma unroll
    for (int r = 0; r < RT; ++r)
#pragma unroll
        for (int c = 0; c < 8; ++c) acc[r][c] = 0.0f;

    loadX(0);
    loadW(0);
    for (int k0 = 0; k0 < K; k0 += KC) {
        __syncthreads();
        stash();
        __syncthreads();
        if (k0 + KC < K) { loadX(k0 + KC); loadW(k0 + KC); }

#pragma unroll
        for (int kc = 0; kc < KC; ++kc) {
            float4 xa = *(const float4*)&Xs[kc][i * RT];
            float4 w0 = *(const float4*)&Ws[kc][c0];
            float4 w1 = *(const float4*)&Ws[kc][c1];
            float xr[RT] = {xa.x, xa.y, xa.z, xa.w};
            float wc[8]  = {w0.x, w0.y, w0.z, w0.w, w1.x, w1.y, w1.z, w1.w};
#pragma unroll
            for (int r = 0; r < RT; ++r)
#pragma unroll
                for (int c = 0; c < 8; ++c)
                    acc[r][c] = fmaf(xr[r], wc[c], acc[r][c]);
        }
    }

    // epilogue: half0 (c0) is always conv; half1 (c1) is conv iff M2==0
    float4 sbv = make_float4(0.f, 0.f, 0.f, 0.f);
    if (M2 != 0) sbv = *(const float4*)&skb[j * 4];
#pragma unroll
    for (int r = 0; r < RT; ++r) {
        int row = r0 + i * RT + r;
        if (row >= N) continue;
        uint2 u0;
        u0.x = (unsigned)f2bf(acc[r][0]) | ((unsigned)f2bf(acc[r][1]) << 16);
        u0.y = (unsigned)f2bf(acc[r][2]) | ((unsigned)f2bf(acc[r][3]) << 16);
        *(uint2*)&H[(size_t)row * M1 + c0] = u0;
        if (M2 == 0) {
            uint2 u1;
            u1.x = (unsigned)f2bf(acc[r][4]) | ((unsigned)f2bf(acc[r][5]) << 16);
            u1.y = (unsigned)f2bf(acc[r][6]) | ((unsigned)f2bf(acc[r][7]) << 16);
            *(uint2*)&H[(size_t)row * M1 + c1] = u1;
        } else {
            float4 s1 = make_float4(acc[r][4] + sbv.x, acc[r][5] + sbv.y,
                                    acc[r][6] + sbv.z, acc[r][7] + sbv.w);
            *(float4*)&SK[(size_t)row * M2 + (c1 - M1)] = s1;
        }
    }
}

// ------------------ fused gather + self + BN + ReLU + residual -------------
// sum = Σ_{edges} H[src]*dinv[src]*dinv[n] + H[n]*dinv[n]^2
// out = relu((sum+bias-m)*g/√(v+eps)+b) + res
template <int M>
__launch_bounds__(256)
__global__ void gather_bn_kernel(const int* __restrict__ rowptr, const int* __restrict__ csr,
                                 const unsigned short* __restrict__ H,
                                 const float* __restrict__ dinv,
                                 const float* __restrict__ bias,
                                 const float* __restrict__ g, const float* __restrict__ b,
                                 const float* __restrict__ m, const float* __restrict__ v,
                                 const float* __restrict__ res, float* __restrict__ out, int N)
{
    constexpr int TPN = M / 8;
    int gid = blockIdx.x * 256 + threadIdx.x;
    int n = gid / TPN;
    if (n >= N) return;
    const int c = (gid % TPN) * 8;

    // fold BN: out_pre = sum * s + o
    float s[8], o[8];
#pragma unroll
    for (int q = 0; q < 2; ++q) {
        float4 gv = *(const float4*)&g[c + q * 4];
        float4 bv = *(const float4*)&b[c + q * 4];
        float4 mv = *(const float4*)&m[c + q * 4];
        float4 vv = *(const float4*)&v[c + q * 4];
        float4 iv = *(const float4*)&bias[c + q * 4];
        float sv[4] = {gv.x * rsqrtf(vv.x + BN_EPS), gv.y * rsqrtf(vv.y + BN_EPS),
                       gv.z * rsqrtf(vv.z + BN_EPS), gv.w * rsqrtf(vv.w + BN_EPS)};
        float bb[4] = {bv.x, bv.y, bv.z, bv.w};
        float mm[4] = {mv.x, mv.y, mv.z, mv.w};
        float ii[4] = {iv.x, iv.y, iv.z, iv.w};
#pragma unroll
        for (int q2 = 0; q2 < 4; ++q2) {
            s[q * 4 + q2] = sv[q2];
            o[q * 4 + q2] = (ii[q2] - mm[q2]) * sv[q2] + bb[q2];
        }
    }

    const float dn = dinv[n];

    // self-loop term
    float acc[8], hf[8];
    uint4 hs = *(const uint4*)&H[(size_t)n * M + c];
    unpack8(hs, hf);
    const float d2 = dn * dn;
#pragma unroll
    for (int k = 0; k < 8; ++k) acc[k] = hf[k] * d2;

    // neighbors (4-unrolled for MLP)
    int p   = rowptr[n];
    int end = rowptr[n + 1];
    for (; p + 3 < end; p += 4) {
        int s0 = csr[p], s1 = csr[p + 1], s2 = csr[p + 2], s3 = csr[p + 3];
        uint4 h0 = *(const uint4*)&H[(size_t)s0 * M + c];
        uint4 h1 = *(const uint4*)&H[(size_t)s1 * M + c];
        uint4 h2 = *(const uint4*)&H[(size_t)s2 * M + c];
        uint4 h3 = *(const uint4*)&H[(size_t)s3 * M + c];
        float w0 = dinv[s0] * dn, w1 = dinv[s1] * dn;
        float w2 = dinv[s2] * dn, w3 = dinv[s3] * dn;
        float f0[8], f1[8], f2[8], f3[8];
        unpack8(h0, f0); unpack8(h1, f1); unpack8(h2, f2); unpack8(h3, f3);
#pragma unroll
        for (int k = 0; k < 8; ++k) acc[k] = fmaf(f0[k], w0, acc[k]);
#pragma unroll
        for (int k = 0; k < 8; ++k) acc[k] = fmaf(f1[k], w1, acc[k]);
#pragma unroll
        for (int k = 0; k < 8; ++k) acc[k] = fmaf(f2[k], w2, acc[k]);
#pragma unroll
        for (int k = 0; k < 8; ++k) acc[k] = fmaf(f3[k], w3, acc[k]);
    }
    for (; p < end; ++p) {
        int s0 = csr[p];
        uint4 h0 = *(const uint4*)&H[(size_t)s0 * M + c];
        float w0 = dinv[s0] * dn;
        float f0[8];
        unpack8(h0, f0);
#pragma unroll
        for (int k = 0; k < 8; ++k) acc[k] = fmaf(f0[k], w0, acc[k]);
    }

    // BN + ReLU + residual
    float4 r0 = *(const float4*)&res[(size_t)n * M + c];
    float4 r1 = *(const float4*)&res[(size_t)n * M + c + 4];
    float rr[8] = {r0.x, r0.y, r0.z, r0.w, r1.x, r1.y, r1.z, r1.w};
    float outv[8];
#pragma unroll
    for (int k = 0; k < 8; ++k)
        outv[k] = fmaxf(fmaf(acc[k], s[k], o[k]), 0.f) + rr[k];
    *(float4*)&out[(size_t)n * M + c]     = make_float4(outv[0], outv[1], outv[2], outv[3]);
    *(float4*)&out[(size_t)n * M + c + 4] = make_float4(outv[4], outv[5], outv[6], outv[7]);
}

// ------------------------- classifier + log_softmax ------------------------
__global__ void classifier_kernel(const float* __restrict__ H2,
                                  const float* __restrict__ W1, const float* __restrict__ B1,
                                  const float* __restrict__ W2, const float* __restrict__ B2,
                                  float* __restrict__ out, int N)
{
    __shared__ float w1s[32 * 16];
    __shared__ float b1s[16];
    __shared__ float w2s[16 * 2];
    __shared__ float b2s[2];
    int tid = threadIdx.x;
    for (int t = tid; t < 512; t += 256) w1s[t] = W1[t];
    if (tid < 16) b1s[tid] = B1[tid];
    if (tid < 32) w2s[tid] = W2[tid];
    if (tid < 2)  b2s[tid] = B2[tid];
    __syncthreads();

    int n = blockIdx.x * 256 + tid;
    if (n >= N) return;

    float x[32];
#pragma unroll
    for (int q = 0; q < 8; ++q) {
        float4 v = *(const float4*)&H2[(size_t)n * 32 + q * 4];
        x[q * 4 + 0] = v.x; x[q * 4 + 1] = v.y; x[q * 4 + 2] = v.z; x[q * 4 + 3] = v.w;
    }
    float h[16];
#pragma unroll
    for (int jj = 0; jj < 16; ++jj) h[jj] = b1s[jj];
#pragma unroll
    for (int k = 0; k < 32; ++k)
#pragma unroll
        for (int jj = 0; jj < 16; ++jj)
            h[jj] = fmaf(x[k], w1s[k * 16 + jj], h[jj]);

    float z0 = b2s[0], z1 = b2s[1];
#pragma unroll
    for (int jj = 0; jj < 16; ++jj) {
        float r = fmaxf(h[jj], 0.f);
        z0 = fmaf(r, w2s[jj * 2 + 0], z0);
        z1 = fmaf(r, w2s[jj * 2 + 1], z1);
    }
    float mx  = fmaxf(z0, z1);
    float lse = mx + logf(expf(z0 - mx) + expf(z1 - mx));
    out[(size_t)n * 2 + 0] = z0 - lse;
    out[(size_t)n * 2 + 1] = z1 - lse;
}

// ------------------------------- launch ------------------------------------
extern "C" void kernel_launch(void* const* d_in, const int* in_sizes, int n_in,
                              void* d_out, int out_size, void* d_ws, size_t ws_size,
                              hipStream_t stream)
{
    const float* x    = (const float*)d_in[0];
    const int*   edge = (const int*)d_in[1];
    const float* W0   = (const float*)d_in[2];
    const float* b0v  = (const float*)d_in[3];
    const float* bn0g = (const float*)d_in[4];
    const float* bn0b = (const float*)d_in[5];
    const float* bn0m = (const float*)d_in[6];
    const float* bn0v = (const float*)d_in[7];
    const float* W1   = (const float*)d_in[8];
    const float* b1v  = (const float*)d_in[9];
    const float* bn1g = (const float*)d_in[10];
    const float* bn1b = (const float*)d_in[11];
    const float* bn1m = (const float*)d_in[12];
    const float* bn1v = (const float*)d_in[13];
    const float* sk1W = (const float*)d_in[14];
    const float* sk1b = (const float*)d_in[15];
    const float* W2   = (const float*)d_in[16];
    const float* b2v  = (const float*)d_in[17];
    const float* bn2g = (const float*)d_in[18];
    const float* bn2b = (const float*)d_in[19];
    const float* bn2m = (const float*)d_in[20];
    const float* bn2v = (const float*)d_in[21];
    const float* sk2W = (const float*)d_in[22];
    const float* sk2b = (const float*)d_in[23];
    const float* c1W  = (const float*)d_in[24];
    const float* c1b  = (const float*)d_in[25];
    const float* c2W  = (const float*)d_in[26];
    const float* c2b  = (const float*)d_in[27];

    const int N = in_sizes[0] / 128;
    const int E = in_sizes[1] / 2;
    const int* src = edge;
    const int* dst = edge + E;

    char*  ws  = (char*)d_ws;
    size_t off = 0;
    auto alloc = [&](size_t bytes) -> char* {
        char* p = ws + off;
        off += (bytes + 255) & ~(size_t)255;
        return p;
    };
    float*          dinv   = (float*)alloc((size_t)N * 4);
    int*            counts = (int*)  alloc((size_t)N * 4);
    int*            excl   = (int*)  alloc((size_t)N * 4);
    int*            rowptr = (int*)  alloc((size_t)(N + 1) * 4);
    int*            bsum   = (int*)  alloc(256 * 4);
    int*            rank   = (int*)  alloc((size_t)E * 4);
    int*            csr    = (int*)  alloc((size_t)E * 4);
    unsigned short* Hb     = (unsigned short*)alloc((size_t)N * 128 * 2);
    float*          SK     = (float*)alloc((size_t)N * 64 * 4);
    float*          Q0     = (float*)alloc((size_t)N * 128 * 4);
    float*          P1     = (float*)alloc((size_t)N * 64 * 4);
    float*          O2     = (float*)alloc((size_t)N * 32 * 4);
    (void)ws_size; (void)n_in; (void)out_size;

    dim3 blk(256);
    auto cdiv = [](int a, int b) { return (a + b - 1) / b; };
    const int nbN = cdiv(N, 256);

    // ---- CSR build (by dst) + dinv ----
    zero_counts_kernel<<<nbN, blk, 0, stream>>>(counts, N);
    rank_hist_kernel<<<cdiv(E, 256), blk, 0, stream>>>(dst, counts, rank, E);
    scan_block_kernel<<<nbN, blk, 0, stream>>>(counts, excl, bsum, N);
    scan_add_kernel<<<cdiv(N + 1, 256), blk, 0, stream>>>(excl, bsum, counts, rowptr, dinv, nbN, N, E);
    fill_csr_kernel<<<cdiv(E, 256), blk, 0, stream>>>(src, dst, rank, rowptr, csr, E);

    // ---- layer 0: 128 -> 128, residual = x ----
    gemm_kernel<128, 128, 0><<<cdiv(N, 64), blk, 0, stream>>>(x, W0, nullptr, nullptr, Hb, nullptr, N);
    gather_bn_kernel<128><<<cdiv(N * 16, 256), blk, 0, stream>>>(
        rowptr, csr, Hb, dinv, b0v, bn0g, bn0b, bn0m, bn0v, x, Q0, N);

    // ---- layer 1: 128 -> 64, skip fused ----
    gemm_kernel<128, 64, 64><<<cdiv(N, 64), blk, 0, stream>>>(Q0, W1, sk1W, sk1b, Hb, SK, N);
    gather_bn_kernel<64><<<cdiv(N * 8, 256), blk, 0, stream>>>(
        rowptr, csr, Hb, dinv, b1v, bn1g, bn1b, bn1m, bn1v, SK, P1, N);

    // ---- layer 2: 64 -> 32, skip fused ----
    gemm_kernel<64, 32, 32><<<cdiv(N, 128), blk, 0, stream>>>(P1, W2, sk2W, sk2b, Hb, SK, N);
    gather_bn_kernel<32><<<cdiv(N * 4, 256), blk, 0, stream>>>(
        rowptr, csr, Hb, dinv, b2v, bn2g, bn2b, bn2m, bn2v, SK, O2, N);

    // ---- classifier + log_softmax ----
    classifier_kernel<<<cdiv(N, 256), blk, 0, stream>>>(O2, c1W, c1b, c2W, c2b, (float*)d_out, N);
}

// Round 6
// 186.048 us; speedup vs baseline: 1.3486x; 1.3486x over previous
//
#include <hip/hip_runtime.h>
#include <hip/hip_bf16.h>
#include <math.h>

// ---------------------------------------------------------------------------
// AdvancedGCN on MI355X — round 6:
//  * GEMMs -> bf16 MFMA (16x16x32), full-K LDS staging, T2 XOR swizzle
//  * weights pre-transposed/converted once per layer (Wt[m][k] bf16)
//  * inter-layer activations bf16 (gather_bn emits bf16 for layers 0,1)
// ---------------------------------------------------------------------------

#define BN_EPS 1e-5f

typedef __attribute__((ext_vector_type(8))) short bf16x8;
typedef __attribute__((ext_vector_type(4))) float f32x4;

static __device__ __forceinline__ float bf2f(unsigned int u16) {
    return __uint_as_float(u16 << 16);
}
static __device__ __forceinline__ unsigned short f2bf(float f) {
    unsigned int b = __float_as_uint(f);
    return (unsigned short)((b + 0x7FFFu + ((b >> 16) & 1u)) >> 16);
}
static __device__ __forceinline__ unsigned int pack2(float a, float b) {
    return (unsigned int)f2bf(a) | ((unsigned int)f2bf(b) << 16);
}
static __device__ __forceinline__ void unpack8(uint4 u, float* f) {
    f[0] = bf2f(u.x & 0xffffu); f[1] = bf2f(u.x >> 16);
    f[2] = bf2f(u.y & 0xffffu); f[3] = bf2f(u.y >> 16);
    f[4] = bf2f(u.z & 0xffffu); f[5] = bf2f(u.z >> 16);
    f[6] = bf2f(u.w & 0xffffu); f[7] = bf2f(u.w >> 16);
}
// swizzled LDS byte offset: row-major rows of rowb bytes, XOR row into 16B slot
static __device__ __forceinline__ int swz(int row, int kb, int rowb) {
    return row * rowb + (kb ^ ((row & 7) << 4));
}

// --------------------------- CSR build kernels -----------------------------
__global__ void zero_counts_kernel(int* __restrict__ counts, int N) {
    int i = blockIdx.x * 256 + threadIdx.x;
    if (i < N) counts[i] = 0;
}

__global__ void rank_hist_kernel(const int* __restrict__ dst, int* __restrict__ counts,
                                 int* __restrict__ rank, int E) {
    int e = blockIdx.x * 256 + threadIdx.x;
    if (e < E) rank[e] = atomicAdd(&counts[dst[e]], 1);
}

__global__ void scan_block_kernel(const int* __restrict__ counts, int* __restrict__ excl,
                                  int* __restrict__ bsum, int N) {
    __shared__ int s[256];
    int tid = threadIdx.x;
    int i = blockIdx.x * 256 + tid;
    int v = (i < N) ? counts[i] : 0;
    s[tid] = v;
    __syncthreads();
#pragma unroll
    for (int off = 1; off < 256; off <<= 1) {
        int t = (tid >= off) ? s[tid - off] : 0;
        __syncthreads();
        s[tid] += t;
        __syncthreads();
    }
    if (i < N) excl[i] = s[tid] - v;
    if (tid == 255) bsum[blockIdx.x] = s[255];
}

__global__ void scan_add_kernel(const int* __restrict__ excl, const int* __restrict__ bsum,
                                const int* __restrict__ counts,
                                int* __restrict__ rowptr, float* __restrict__ dinv,
                                int nb, int N, int E) {
    __shared__ int sb[256];
    int tid = threadIdx.x;
    int v = (tid < nb) ? bsum[tid] : 0;
    sb[tid] = v;
    __syncthreads();
#pragma unroll
    for (int off = 1; off < 256; off <<= 1) {
        int t = (tid >= off) ? sb[tid - off] : 0;
        __syncthreads();
        sb[tid] += t;
        __syncthreads();
    }
    int eb = sb[blockIdx.x] - ((blockIdx.x < nb) ? bsum[blockIdx.x] : 0);  // exclusive
    int i = blockIdx.x * 256 + tid;
    if (i < N) {
        rowptr[i] = excl[i] + eb;
        dinv[i]   = rsqrtf((float)counts[i] + 1.0f);
    }
    if (i == N) rowptr[N] = E;
}

__global__ void fill_csr_kernel(const int* __restrict__ src, const int* __restrict__ dst,
                                const int* __restrict__ rank, const int* __restrict__ rowptr,
                                int* __restrict__ csr, int E) {
    int e = blockIdx.x * 256 + threadIdx.x;
    if (e >= E) return;
    csr[rowptr[dst[e]] + rank[e]] = src[e];
}

// -------------------- weight transpose + bf16 convert ----------------------
// Wt[m][k] = bf16( m < M1 ? Wc[k][m] : Wsk[k][m-M1] )
template <int K, int M1, int M2>
__global__ void wt_build_kernel(const float* __restrict__ Wc, const float* __restrict__ Wsk,
                                unsigned short* __restrict__ Wt) {
    constexpr int M = M1 + M2;
    int idx = blockIdx.x * 256 + threadIdx.x;
    if (idx >= M * K) return;
    int m = idx / K, k = idx % K;
    float v = (M2 == 0 || m < M1) ? Wc[(size_t)k * M1 + m]
                                  : Wsk[(size_t)k * M2 + (m - M1)];
    Wt[idx] = f2bf(v);
}

// ----------------------------- MFMA dual GEMM ------------------------------
// H(bf16)[N,M1] = X @ Wc ; SK(f32)[N,M2] = X @ Wsk + skb (cols M1..M-1)
// Block: 256 thr / 4 waves; tile BM x M, BM = 8192/M; per-wave 32x64 (2x4 frags).
// Full K staged in LDS (K <= 128), XOR-swizzled; mfma_f32_16x16x32_bf16.
template <int K, int M1, int M2, bool IN_BF16>
__launch_bounds__(256)
__global__ void mfma_gemm_kernel(const float* __restrict__ Xf,
                                 const unsigned short* __restrict__ Xb,
                                 const unsigned short* __restrict__ Wt,
                                 const float* __restrict__ skb,
                                 unsigned short* __restrict__ H,
                                 float* __restrict__ SK, int N)
{
    constexpr int M    = M1 + M2;
    constexpr int BM   = 8192 / M;          // 64 (M=128) or 128 (M=64)
    constexpr int WC   = M / 64;            // wave cols
    constexpr int ROWB = K * 2;             // LDS row bytes
    constexpr int CPR  = K / 8;             // 16B chunks per row
    constexpr int WCH  = (M * K) / 2048;    // Wt chunks per thread

    __shared__ unsigned char XsB[BM * K * 2];
    __shared__ unsigned char WsB[M * K * 2];

    const int tid = threadIdx.x;
    const int r0  = blockIdx.x * BM;

    // ---- stage X tile (BM x K) as bf16, swizzled ----
#pragma unroll
    for (int c = 0; c < 4; ++c) {           // BM*K/8/256 == 4 for all layers
        int q   = tid + 256 * c;
        int row = q / CPR, kq = q % CPR;
        int grow = r0 + row;
        uint4 u = make_uint4(0u, 0u, 0u, 0u);
        if (IN_BF16) {
            if (grow < N) u = *(const uint4*)(Xb + (size_t)grow * K + kq * 8);
        } else {
            if (grow < N) {
                const float* p = Xf + (size_t)grow * K + kq * 8;
                float4 v0 = *(const float4*)p;
                float4 v1 = *(const float4*)(p + 4);
                u.x = pack2(v0.x, v0.y); u.y = pack2(v0.z, v0.w);
                u.z = pack2(v1.x, v1.y); u.w = pack2(v1.z, v1.w);
            }
        }
        *(uint4*)(XsB + swz(row, kq * 16, ROWB)) = u;
    }
    // ---- stage Wt (M x K) bf16, swizzled ----
#pragma unroll
    for (int c = 0; c < WCH; ++c) {
        int q = tid + 256 * c;
        int m = q / CPR, kq = q % CPR;
        uint4 u = *(const uint4*)(Wt + (size_t)m * K + kq * 8);
        *(uint4*)(WsB + swz(m, kq * 16, ROWB)) = u;
    }
    __syncthreads();

    const int lane = tid & 63, wid = tid >> 6;
    const int wr = wid / WC, wc = wid % WC;
    const int lrow = lane & 15;
    const int kb   = (lane >> 4) << 4;      // this lane's 16B k-slot

    f32x4 acc[2][4];
#pragma unroll
    for (int fi = 0; fi < 2; ++fi)
#pragma unroll
        for (int fj = 0; fj < 4; ++fj)
            acc[fi][fj] = (f32x4){0.f, 0.f, 0.f, 0.f};

#pragma unroll
    for (int ks = 0; ks < K / 32; ++ks) {
        const int kb0 = ks * 64 + kb;
        bf16x8 a0 = *(const bf16x8*)(XsB + swz(wr * 32 +      lrow, kb0, ROWB));
        bf16x8 a1 = *(const bf16x8*)(XsB + swz(wr * 32 + 16 + lrow, kb0, ROWB));
        bf16x8 b0 = *(const bf16x8*)(WsB + swz(wc * 64 +      lrow, kb0, ROWB));
        bf16x8 b1 = *(const bf16x8*)(WsB + swz(wc * 64 + 16 + lrow, kb0, ROWB));
        bf16x8 b2 = *(const bf16x8*)(WsB + swz(wc * 64 + 32 + lrow, kb0, ROWB));
        bf16x8 b3 = *(const bf16x8*)(WsB + swz(wc * 64 + 48 + lrow, kb0, ROWB));
        acc[0][0] = __builtin_amdgcn_mfma_f32_16x16x32_bf16(a0, b0, acc[0][0], 0, 0, 0);
        acc[0][1] = __builtin_amdgcn_mfma_f32_16x16x32_bf16(a0, b1, acc[0][1], 0, 0, 0);
        acc[0][2] = __builtin_amdgcn_mfma_f32_16x16x32_bf16(a0, b2, acc[0][2], 0, 0, 0);
        acc[0][3] = __builtin_amdgcn_mfma_f32_16x16x32_bf16(a0, b3, acc[0][3], 0, 0, 0);
        acc[1][0] = __builtin_amdgcn_mfma_f32_16x16x32_bf16(a1, b0, acc[1][0], 0, 0, 0);
        acc[1][1] = __builtin_amdgcn_mfma_f32_16x16x32_bf16(a1, b1, acc[1][1], 0, 0, 0);
        acc[1][2] = __builtin_amdgcn_mfma_f32_16x16x32_bf16(a1, b2, acc[1][2], 0, 0, 0);
        acc[1][3] = __builtin_amdgcn_mfma_f32_16x16x32_bf16(a1, b3, acc[1][3], 0, 0, 0);
    }

    // ---- epilogue: D[row][col], col = lane&15, row = (lane>>4)*4 + r ----
    const int orow0 = r0 + wr * 32 + (lane >> 4) * 4;
#pragma unroll
    for (int fi = 0; fi < 2; ++fi) {
#pragma unroll
        for (int fj = 0; fj < 4; ++fj) {
            const int col = wc * 64 + fj * 16 + lrow;
            const bool conv = (M2 == 0) || (col < M1);
            const float sb = conv ? 0.f : skb[col - M1];
#pragma unroll
            for (int r = 0; r < 4; ++r) {
                const int row = orow0 + fi * 16 + r;
                if (row >= N) continue;
                const float val = acc[fi][fj][r];
                if (conv) H[(size_t)row * M1 + col] = f2bf(val);
                else      SK[(size_t)row * M2 + (col - M1)] = val + sb;
            }
        }
    }
}

// ------------------ fused gather + self + BN + ReLU + residual -------------
// sum = Σ_{edges} H[src]*dinv[src]*dinv[n] + H[n]*dinv[n]^2
// out = relu((sum+bias-m)*g/√(v+eps)+b) + res    (out bf16 or f32)
template <int M, bool OUT_BF16>
__launch_bounds__(256)
__global__ void gather_bn_kernel(const int* __restrict__ rowptr, const int* __restrict__ csr,
                                 const unsigned short* __restrict__ H,
                                 const float* __restrict__ dinv,
                                 const float* __restrict__ bias,
                                 const float* __restrict__ g, const float* __restrict__ b,
                                 const float* __restrict__ m, const float* __restrict__ v,
                                 const float* __restrict__ res, void* __restrict__ out, int N)
{
    constexpr int TPN = M / 8;
    int gid = blockIdx.x * 256 + threadIdx.x;
    int n = gid / TPN;
    if (n >= N) return;
    const int c = (gid % TPN) * 8;

    // fold BN: out_pre = sum * s + o
    float s[8], o[8];
#pragma unroll
    for (int q = 0; q < 2; ++q) {
        float4 gv = *(const float4*)&g[c + q * 4];
        float4 bv = *(const float4*)&b[c + q * 4];
        float4 mv = *(const float4*)&m[c + q * 4];
        float4 vv = *(const float4*)&v[c + q * 4];
        float4 iv = *(const float4*)&bias[c + q * 4];
        float sv[4] = {gv.x * rsqrtf(vv.x + BN_EPS), gv.y * rsqrtf(vv.y + BN_EPS),
                       gv.z * rsqrtf(vv.z + BN_EPS), gv.w * rsqrtf(vv.w + BN_EPS)};
        float bb[4] = {bv.x, bv.y, bv.z, bv.w};
        float mm[4] = {mv.x, mv.y, mv.z, mv.w};
        float ii[4] = {iv.x, iv.y, iv.z, iv.w};
#pragma unroll
        for (int q2 = 0; q2 < 4; ++q2) {
            s[q * 4 + q2] = sv[q2];
            o[q * 4 + q2] = (ii[q2] - mm[q2]) * sv[q2] + bb[q2];
        }
    }

    const float dn = dinv[n];

    float acc[8], hf[8];
    uint4 hs = *(const uint4*)&H[(size_t)n * M + c];
    unpack8(hs, hf);
    const float d2 = dn * dn;
#pragma unroll
    for (int k = 0; k < 8; ++k) acc[k] = hf[k] * d2;

    int p   = rowptr[n];
    int end = rowptr[n + 1];
    for (; p + 3 < end; p += 4) {
        int s0 = csr[p], s1 = csr[p + 1], s2 = csr[p + 2], s3 = csr[p + 3];
        uint4 h0 = *(const uint4*)&H[(size_t)s0 * M + c];
        uint4 h1 = *(const uint4*)&H[(size_t)s1 * M + c];
        uint4 h2 = *(const uint4*)&H[(size_t)s2 * M + c];
        uint4 h3 = *(const uint4*)&H[(size_t)s3 * M + c];
        float w0 = dinv[s0] * dn, w1 = dinv[s1] * dn;
        float w2 = dinv[s2] * dn, w3 = dinv[s3] * dn;
        float f0[8], f1[8], f2[8], f3[8];
        unpack8(h0, f0); unpack8(h1, f1); unpack8(h2, f2); unpack8(h3, f3);
#pragma unroll
        for (int k = 0; k < 8; ++k) acc[k] = fmaf(f0[k], w0, acc[k]);
#pragma unroll
        for (int k = 0; k < 8; ++k) acc[k] = fmaf(f1[k], w1, acc[k]);
#pragma unroll
        for (int k = 0; k < 8; ++k) acc[k] = fmaf(f2[k], w2, acc[k]);
#pragma unroll
        for (int k = 0; k < 8; ++k) acc[k] = fmaf(f3[k], w3, acc[k]);
    }
    for (; p < end; ++p) {
        int s0 = csr[p];
        uint4 h0 = *(const uint4*)&H[(size_t)s0 * M + c];
        float w0 = dinv[s0] * dn;
        float f0[8];
        unpack8(h0, f0);
#pragma unroll
        for (int k = 0; k < 8; ++k) acc[k] = fmaf(f0[k], w0, acc[k]);
    }

    float4 r0 = *(const float4*)&res[(size_t)n * M + c];
    float4 r1 = *(const float4*)&res[(size_t)n * M + c + 4];
    float rr[8] = {r0.x, r0.y, r0.z, r0.w, r1.x, r1.y, r1.z, r1.w};
    float outv[8];
#pragma unroll
    for (int k = 0; k < 8; ++k)
        outv[k] = fmaxf(fmaf(acc[k], s[k], o[k]), 0.f) + rr[k];

    if (OUT_BF16) {
        uint4 u;
        u.x = pack2(outv[0], outv[1]); u.y = pack2(outv[2], outv[3]);
        u.z = pack2(outv[4], outv[5]); u.w = pack2(outv[6], outv[7]);
        *(uint4*)&((unsigned short*)out)[(size_t)n * M + c] = u;
    } else {
        float* op = (float*)out;
        *(float4*)&op[(size_t)n * M + c]     = make_float4(outv[0], outv[1], outv[2], outv[3]);
        *(float4*)&op[(size_t)n * M + c + 4] = make_float4(outv[4], outv[5], outv[6], outv[7]);
    }
}

// ------------------------- classifier + log_softmax ------------------------
__global__ void classifier_kernel(const float* __restrict__ H2,
                                  const float* __restrict__ W1, const float* __restrict__ B1,
                                  const float* __restrict__ W2, const float* __restrict__ B2,
                                  float* __restrict__ out, int N)
{
    __shared__ float w1s[32 * 16];
    __shared__ float b1s[16];
    __shared__ float w2s[16 * 2];
    __shared__ float b2s[2];
    int tid = threadIdx.x;
    for (int t = tid; t < 512; t += 256) w1s[t] = W1[t];
    if (tid < 16) b1s[tid] = B1[tid];
    if (tid < 32) w2s[tid] = W2[tid];
    if (tid < 2)  b2s[tid] = B2[tid];
    __syncthreads();

    int n = blockIdx.x * 256 + tid;
    if (n >= N) return;

    float x[32];
#pragma unroll
    for (int q = 0; q < 8; ++q) {
        float4 v = *(const float4*)&H2[(size_t)n * 32 + q * 4];
        x[q * 4 + 0] = v.x; x[q * 4 + 1] = v.y; x[q * 4 + 2] = v.z; x[q * 4 + 3] = v.w;
    }
    float h[16];
#pragma unroll
    for (int jj = 0; jj < 16; ++jj) h[jj] = b1s[jj];
#pragma unroll
    for (int k = 0; k < 32; ++k)
#pragma unroll
        for (int jj = 0; jj < 16; ++jj)
            h[jj] = fmaf(x[k], w1s[k * 16 + jj], h[jj]);

    float z0 = b2s[0], z1 = b2s[1];
#pragma unroll
    for (int jj = 0; jj < 16; ++jj) {
        float r = fmaxf(h[jj], 0.f);
        z0 = fmaf(r, w2s[jj * 2 + 0], z0);
        z1 = fmaf(r, w2s[jj * 2 + 1], z1);
    }
    float mx  = fmaxf(z0, z1);
    float lse = mx + logf(expf(z0 - mx) + expf(z1 - mx));
    out[(size_t)n * 2 + 0] = z0 - lse;
    out[(size_t)n * 2 + 1] = z1 - lse;
}

// ------------------------------- launch ------------------------------------
extern "C" void kernel_launch(void* const* d_in, const int* in_sizes, int n_in,
                              void* d_out, int out_size, void* d_ws, size_t ws_size,
                              hipStream_t stream)
{
    const float* x    = (const float*)d_in[0];
    const int*   edge = (const int*)d_in[1];
    const float* W0   = (const float*)d_in[2];
    const float* b0v  = (const float*)d_in[3];
    const float* bn0g = (const float*)d_in[4];
    const float* bn0b = (const float*)d_in[5];
    const float* bn0m = (const float*)d_in[6];
    const float* bn0v = (const float*)d_in[7];
    const float* W1   = (const float*)d_in[8];
    const float* b1v  = (const float*)d_in[9];
    const float* bn1g = (const float*)d_in[10];
    const float* bn1b = (const float*)d_in[11];
    const float* bn1m = (const float*)d_in[12];
    const float* bn1v = (const float*)d_in[13];
    const float* sk1W = (const float*)d_in[14];
    const float* sk1b = (const float*)d_in[15];
    const float* W2   = (const float*)d_in[16];
    const float* b2v  = (const float*)d_in[17];
    const float* bn2g = (const float*)d_in[18];
    const float* bn2b = (const float*)d_in[19];
    const float* bn2m = (const float*)d_in[20];
    const float* bn2v = (const float*)d_in[21];
    const float* sk2W = (const float*)d_in[22];
    const float* sk2b = (const float*)d_in[23];
    const float* c1W  = (const float*)d_in[24];
    const float* c1b  = (const float*)d_in[25];
    const float* c2W  = (const float*)d_in[26];
    const float* c2b  = (const float*)d_in[27];

    const int N = in_sizes[0] / 128;
    const int E = in_sizes[1] / 2;
    const int* src = edge;
    const int* dst = edge + E;

    char*  ws  = (char*)d_ws;
    size_t off = 0;
    auto alloc = [&](size_t bytes) -> char* {
        char* p = ws + off;
        off += (bytes + 255) & ~(size_t)255;
        return p;
    };
    float*          dinv   = (float*)alloc((size_t)N * 4);
    int*            counts = (int*)  alloc((size_t)N * 4);
    int*            excl   = (int*)  alloc((size_t)N * 4);
    int*            rowptr = (int*)  alloc((size_t)(N + 1) * 4);
    int*            bsum   = (int*)  alloc(256 * 4);
    int*            rank   = (int*)  alloc((size_t)E * 4);
    int*            csr    = (int*)  alloc((size_t)E * 4);
    unsigned short* Hb     = (unsigned short*)alloc((size_t)N * 128 * 2);
    float*          SK     = (float*)alloc((size_t)N * 64 * 4);
    unsigned short* Q0     = (unsigned short*)alloc((size_t)N * 128 * 2);
    unsigned short* P1     = (unsigned short*)alloc((size_t)N * 64 * 2);
    float*          O2     = (float*)alloc((size_t)N * 32 * 4);
    unsigned short* Wt0    = (unsigned short*)alloc(128 * 128 * 2);
    unsigned short* Wt1    = (unsigned short*)alloc(128 * 128 * 2);
    unsigned short* Wt2    = (unsigned short*)alloc(64 * 64 * 2);
    (void)ws_size; (void)n_in; (void)out_size;

    dim3 blk(256);
    auto cdiv = [](int a, int b) { return (a + b - 1) / b; };
    const int nbN = cdiv(N, 256);

    // ---- CSR build (by dst) + dinv ----
    zero_counts_kernel<<<nbN, blk, 0, stream>>>(counts, N);
    rank_hist_kernel<<<cdiv(E, 256), blk, 0, stream>>>(dst, counts, rank, E);
    scan_block_kernel<<<nbN, blk, 0, stream>>>(counts, excl, bsum, N);
    scan_add_kernel<<<cdiv(N + 1, 256), blk, 0, stream>>>(excl, bsum, counts, rowptr, dinv, nbN, N, E);
    fill_csr_kernel<<<cdiv(E, 256), blk, 0, stream>>>(src, dst, rank, rowptr, csr, E);

    // ---- weight transpose/convert ----
    wt_build_kernel<128, 128, 0><<<64, blk, 0, stream>>>(W0, nullptr, Wt0);
    wt_build_kernel<128, 64, 64><<<64, blk, 0, stream>>>(W1, sk1W, Wt1);
    wt_build_kernel<64, 32, 32><<<16, blk, 0, stream>>>(W2, sk2W, Wt2);

    // ---- layer 0: 128 -> 128, residual = x ----
    mfma_gemm_kernel<128, 128, 0, false><<<cdiv(N, 64), blk, 0, stream>>>(
        x, nullptr, Wt0, nullptr, Hb, nullptr, N);
    gather_bn_kernel<128, true><<<cdiv(N * 16, 256), blk, 0, stream>>>(
        rowptr, csr, Hb, dinv, b0v, bn0g, bn0b, bn0m, bn0v, x, Q0, N);

    // ---- layer 1: 128 -> 64, skip fused ----
    mfma_gemm_kernel<128, 64, 64, true><<<cdiv(N, 64), blk, 0, stream>>>(
        nullptr, Q0, Wt1, sk1b, Hb, SK, N);
    gather_bn_kernel<64, true><<<cdiv(N * 8, 256), blk, 0, stream>>>(
        rowptr, csr, Hb, dinv, b1v, bn1g, bn1b, bn1m, bn1v, SK, P1, N);

    // ---- layer 2: 64 -> 32, skip fused ----
    mfma_gemm_kernel<64, 32, 32, true><<<cdiv(N, 128), blk, 0, stream>>>(
        nullptr, P1, Wt2, sk2b, Hb, SK, N);
    gather_bn_kernel<32, false><<<cdiv(N * 4, 256), blk, 0, stream>>>(
        rowptr, csr, Hb, dinv, b2v, bn2g, bn2b, bn2m, bn2v, SK, O2, N);

    // ---- classifier + log_softmax ----
    classifier_kernel<<<cdiv(N, 256), blk, 0, stream>>>(O2, c1W, c1b, c2W, c2b, (float*)d_out, N);
}